// Round 1
// baseline (6728.616 us; speedup 1.0000x reference)
//
#include <hip/hip_runtime.h>
#include <stdint.h>

#define HH 64
#define G4 256
#define TT 512
#define BB 1024
#define BT 8

__device__ __forceinline__ float fast_rcp(float x){ return __builtin_amdgcn_rcpf(x); }
__device__ __forceinline__ float sigf(float x){ return fast_rcp(1.f + __expf(-x)); }
__device__ __forceinline__ float tanh_f(float x){
  float xx = fminf(fmaxf(x, -20.f), 20.f);
  float e = __expf(2.f * xx);
  return (e - 1.f) * fast_rcp(e + 1.f);
}
__device__ __forceinline__ uint32_t f2bf_u(float f){
  union { float f; uint32_t u; } v; v.f = f;
  return (v.u + 0x7fffu + ((v.u >> 16) & 1u)) >> 16;
}
__device__ __forceinline__ float bfbits_lo(uint32_t w){
  union { uint32_t u; float f; } v; v.u = w << 16; return v.f;
}
__device__ __forceinline__ float bfbits_hi(uint32_t w){
  union { uint32_t u; float f; } v; v.u = w & 0xffff0000u; return v.f;
}

template<typename YT> struct YOps;
template<> struct YOps<float>{
  static __device__ __forceinline__ void store(float* p, float v){ *p = v; }
  static __device__ __forceinline__ float4 load4(const float* p){ return *(const float4*)p; }
};
template<> struct YOps<unsigned short>{
  static __device__ __forceinline__ void store(unsigned short* p, float v){ *p = (unsigned short)f2bf_u(v); }
  static __device__ __forceinline__ float4 load4(const unsigned short* p){
    ushort4 u = *(const ushort4*)p;
    float4 r;
    r.x = bfbits_lo((uint32_t)u.x);
    r.y = bfbits_lo((uint32_t)u.y);
    r.z = bfbits_lo((uint32_t)u.z);
    r.w = bfbits_lo((uint32_t)u.w);
    return r;
  }
};

// ---------------- Layer 0: input dim 3, weights fp32 in registers ----------------
template<typename YT>
__global__ __launch_bounds__(256, 1) void lstm_l0_kernel(
    const float* __restrict__ x,   // [B][3][T]
    const float* __restrict__ Wih_f, const float* __restrict__ Whh_f,
    const float* __restrict__ bih_f, const float* __restrict__ bhh_f,
    const float* __restrict__ Wih_b, const float* __restrict__ Whh_b,
    const float* __restrict__ bih_b, const float* __restrict__ bhh_b,
    YT* __restrict__ y0)           // [B][T][128]
{
  const int tid = threadIdx.x;
  const int j = tid;                       // gate row 0..255
  const int dir = blockIdx.y;
  const int bbase = blockIdx.x * BT;
  const float* Wih = dir ? Wih_b : Wih_f;
  const float* Whh = dir ? Whh_b : Whh_f;
  const float* bih = dir ? bih_b : bih_f;
  const float* bhh = dir ? bhh_b : bhh_f;

  __shared__ float sH[BT][HH];
  __shared__ float sG[BT][G4];
  __shared__ float sX[2][BT][4];

  // weight row j in registers (fp32)
  float wh[HH];
  #pragma unroll
  for (int q = 0; q < HH / 4; q++){
    float4 v = *(const float4*)(Whh + j * HH + q * 4);
    wh[4*q] = v.x; wh[4*q+1] = v.y; wh[4*q+2] = v.z; wh[4*q+3] = v.w;
  }
  const float wi0 = Wih[j*3+0], wi1 = Wih[j*3+1], wi2 = Wih[j*3+2];
  const float bias = bih[j] + bhh[j];

  // zero h state
  sH[tid >> 6][tid & 63] = 0.f;
  sH[4 + (tid >> 6)][tid & 63] = 0.f;

  const int xbt = tid / 3, xd = tid % 3;
  const bool xload = (tid < 24);
  const int t0 = dir ? (TT - 1) : 0;
  if (xload) sX[0][xbt][xd] = x[(size_t)(bbase + xbt) * 1536 + xd * 512 + t0];
  __syncthreads();

  float c0 = 0.f, c1 = 0.f;
  const int bt0 = tid >> 6, u0 = tid & 63;
  const int bt1 = bt0 + 4;

  for (int s = 0; s < TT; s++){
    const int t  = dir ? (TT - 1 - s) : s;
    const int tn = dir ? (TT - 2 - s) : (s + 1);
    float xpre = 0.f;
    if (xload && (s + 1 < TT)) xpre = x[(size_t)(bbase + xbt) * 1536 + xd * 512 + tn];

    const int cur = s & 1;
    // ---- phase A: gate preactivations ----
    float acc[BT];
    #pragma unroll
    for (int bt = 0; bt < BT; bt++){
      acc[bt] = fmaf(wi0, sX[cur][bt][0],
                fmaf(wi1, sX[cur][bt][1],
                fmaf(wi2, sX[cur][bt][2], bias)));
    }
    #pragma unroll
    for (int q = 0; q < HH / 4; q++){
      #pragma unroll
      for (int bt = 0; bt < BT; bt++){
        float4 h4 = *(const float4*)&sH[bt][4*q];
        acc[bt] = fmaf(wh[4*q],   h4.x, acc[bt]);
        acc[bt] = fmaf(wh[4*q+1], h4.y, acc[bt]);
        acc[bt] = fmaf(wh[4*q+2], h4.z, acc[bt]);
        acc[bt] = fmaf(wh[4*q+3], h4.w, acc[bt]);
      }
    }
    #pragma unroll
    for (int bt = 0; bt < BT; bt++) sG[bt][j] = acc[bt];
    if (xload) sX[cur ^ 1][xbt][xd] = xpre;
    __syncthreads();

    // ---- phase B: gate nonlinearity + state update ----
    {
      float i0 = sigf(sG[bt0][u0]);
      float f0 = sigf(sG[bt0][u0 + 64]);
      float g0 = tanh_f(sG[bt0][u0 + 128]);
      float o0 = sigf(sG[bt0][u0 + 192]);
      c0 = fmaf(f0, c0, i0 * g0);
      float h0v = o0 * tanh_f(c0);
      sH[bt0][u0] = h0v;
      YOps<YT>::store(y0 + ((size_t)(bbase + bt0) * TT + t) * 128 + dir * 64 + u0, h0v);

      float i1 = sigf(sG[bt1][u0]);
      float f1 = sigf(sG[bt1][u0 + 64]);
      float g1 = tanh_f(sG[bt1][u0 + 128]);
      float o1 = sigf(sG[bt1][u0 + 192]);
      c1 = fmaf(f1, c1, i1 * g1);
      float h1v = o1 * tanh_f(c1);
      sH[bt1][u0] = h1v;
      YOps<YT>::store(y0 + ((size_t)(bbase + bt1) * TT + t) * 128 + dir * 64 + u0, h1v);
    }
    __syncthreads();
  }
}

// ---------------- Layer 1: input dim 128 (y0), Wih bf16-packed regs, Whh fp32 regs --------
template<typename YT>
__global__ __launch_bounds__(256, 1) void lstm_l1_kernel(
    const YT* __restrict__ y0,     // [B][T][128]
    const float* __restrict__ Wih_f, const float* __restrict__ Whh_f,
    const float* __restrict__ bih_f, const float* __restrict__ bhh_f,
    const float* __restrict__ Wih_b, const float* __restrict__ Whh_b,
    const float* __restrict__ bih_b, const float* __restrict__ bhh_b,
    float* __restrict__ hT)        // [B][128]
{
  const int tid = threadIdx.x;
  const int j = tid;
  const int dir = blockIdx.y;
  const int bbase = blockIdx.x * BT;
  const float* Wih = dir ? Wih_b : Wih_f;
  const float* Whh = dir ? Whh_b : Whh_f;
  const float* bih = dir ? bih_b : bih_f;
  const float* bhh = dir ? bhh_b : bhh_f;

  __shared__ float sH[BT][HH];
  __shared__ float sG[BT][G4];
  __shared__ float sY[2][BT][128];

  // Wih row j: 128 weights as 64 packed-bf16 dwords
  uint32_t wip[64];
  #pragma unroll
  for (int q = 0; q < 32; q++){
    float4 v = *(const float4*)(Wih + j * 128 + q * 4);
    wip[2*q]   = f2bf_u(v.x) | (f2bf_u(v.y) << 16);
    wip[2*q+1] = f2bf_u(v.z) | (f2bf_u(v.w) << 16);
  }
  // Whh row j: fp32
  float wh[HH];
  #pragma unroll
  for (int q = 0; q < HH / 4; q++){
    float4 v = *(const float4*)(Whh + j * HH + q * 4);
    wh[4*q] = v.x; wh[4*q+1] = v.y; wh[4*q+2] = v.z; wh[4*q+3] = v.w;
  }
  const float bias = bih[j] + bhh[j];

  sH[tid >> 6][tid & 63] = 0.f;
  sH[4 + (tid >> 6)][tid & 63] = 0.f;

  const int pbt = tid >> 5;
  const int pc4 = (tid & 31) * 4;
  const int t0 = dir ? (TT - 1) : 0;
  {
    float4 v = YOps<YT>::load4(y0 + ((size_t)(bbase + pbt) * TT + t0) * 128 + pc4);
    sY[0][pbt][pc4]   = v.x; sY[0][pbt][pc4+1] = v.y;
    sY[0][pbt][pc4+2] = v.z; sY[0][pbt][pc4+3] = v.w;
  }
  __syncthreads();

  float c0 = 0.f, c1 = 0.f;
  const int bt0 = tid >> 6, u0 = tid & 63;
  const int bt1 = bt0 + 4;

  for (int s = 0; s < TT; s++){
    const int tn = dir ? (TT - 2 - s) : (s + 1);
    float4 ypre = make_float4(0.f, 0.f, 0.f, 0.f);
    if (s + 1 < TT) ypre = YOps<YT>::load4(y0 + ((size_t)(bbase + pbt) * TT + tn) * 128 + pc4);

    const int cur = s & 1;
    float acc[BT];
    #pragma unroll
    for (int bt = 0; bt < BT; bt++) acc[bt] = bias;

    // input GEMM part: K=128 from staged y0
    #pragma unroll
    for (int q = 0; q < 32; q++){
      const float w0 = bfbits_lo(wip[2*q]);
      const float w1 = bfbits_hi(wip[2*q]);
      const float w2 = bfbits_lo(wip[2*q+1]);
      const float w3 = bfbits_hi(wip[2*q+1]);
      #pragma unroll
      for (int bt = 0; bt < BT; bt++){
        float4 y4 = *(const float4*)&sY[cur][bt][4*q];
        acc[bt] = fmaf(w0, y4.x, acc[bt]);
        acc[bt] = fmaf(w1, y4.y, acc[bt]);
        acc[bt] = fmaf(w2, y4.z, acc[bt]);
        acc[bt] = fmaf(w3, y4.w, acc[bt]);
      }
    }
    // recurrent part: K=64
    #pragma unroll
    for (int q = 0; q < HH / 4; q++){
      #pragma unroll
      for (int bt = 0; bt < BT; bt++){
        float4 h4 = *(const float4*)&sH[bt][4*q];
        acc[bt] = fmaf(wh[4*q],   h4.x, acc[bt]);
        acc[bt] = fmaf(wh[4*q+1], h4.y, acc[bt]);
        acc[bt] = fmaf(wh[4*q+2], h4.z, acc[bt]);
        acc[bt] = fmaf(wh[4*q+3], h4.w, acc[bt]);
      }
    }
    #pragma unroll
    for (int bt = 0; bt < BT; bt++) sG[bt][j] = acc[bt];
    {
      const int nb = cur ^ 1;
      sY[nb][pbt][pc4]   = ypre.x; sY[nb][pbt][pc4+1] = ypre.y;
      sY[nb][pbt][pc4+2] = ypre.z; sY[nb][pbt][pc4+3] = ypre.w;
    }
    __syncthreads();

    float i0 = sigf(sG[bt0][u0]);
    float f0 = sigf(sG[bt0][u0 + 64]);
    float g0 = tanh_f(sG[bt0][u0 + 128]);
    float o0 = sigf(sG[bt0][u0 + 192]);
    c0 = fmaf(f0, c0, i0 * g0);
    float h0v = o0 * tanh_f(c0);
    sH[bt0][u0] = h0v;

    float i1 = sigf(sG[bt1][u0]);
    float f1 = sigf(sG[bt1][u0 + 64]);
    float g1 = tanh_f(sG[bt1][u0 + 128]);
    float o1 = sigf(sG[bt1][u0 + 192]);
    c1 = fmaf(f1, c1, i1 * g1);
    float h1v = o1 * tanh_f(c1);
    sH[bt1][u0] = h1v;

    if (s == TT - 1){
      hT[(size_t)(bbase + bt0) * 128 + dir * 64 + u0] = h0v;
      hT[(size_t)(bbase + bt1) * 128 + dir * 64 + u0] = h1v;
    }
    __syncthreads();
  }
}

// ---------------- FC head: relu(hT @ fc1W^T + b1) @ fc2W^T + b2 ----------------
__global__ __launch_bounds__(256, 1) void fc_kernel(
    const float* __restrict__ hT,   // [B][128]
    const float* __restrict__ w1, const float* __restrict__ b1,
    const float* __restrict__ w2, const float* __restrict__ b2,
    float* __restrict__ out)        // [B][2]
{
  __shared__ float sh[4][64];
  const int wave = threadIdx.x >> 6, lane = threadIdx.x & 63;
  const int b = blockIdx.x * 4 + wave;
  float acc = b1[lane];
  const float* hrow = hT + (size_t)b * 128;
  #pragma unroll
  for (int k = 0; k < 128; k += 4){
    float4 h4 = *(const float4*)(hrow + k);
    float4 w4 = *(const float4*)(w1 + lane * 128 + k);
    acc = fmaf(w4.x, h4.x, acc);
    acc = fmaf(w4.y, h4.y, acc);
    acc = fmaf(w4.z, h4.z, acc);
    acc = fmaf(w4.w, h4.w, acc);
  }
  sh[wave][lane] = fmaxf(acc, 0.f);
  __syncthreads();
  if (lane < 2){
    float a = b2[lane];
    #pragma unroll
    for (int k = 0; k < 64; k++) a = fmaf(w2[lane * 64 + k], sh[wave][k], a);
    out[(size_t)b * 2 + lane] = a;
  }
}

template<typename YT>
static void run_all(const void* const* d_in, void* d_out, void* d_ws, hipStream_t stream){
  const float* x     = (const float*)d_in[0];
  const float* Wih0f = (const float*)d_in[1];
  const float* Whh0f = (const float*)d_in[2];
  const float* bih0f = (const float*)d_in[3];
  const float* bhh0f = (const float*)d_in[4];
  const float* Wih0b = (const float*)d_in[5];
  const float* Whh0b = (const float*)d_in[6];
  const float* bih0b = (const float*)d_in[7];
  const float* bhh0b = (const float*)d_in[8];
  const float* Wih1f = (const float*)d_in[9];
  const float* Whh1f = (const float*)d_in[10];
  const float* bih1f = (const float*)d_in[11];
  const float* bhh1f = (const float*)d_in[12];
  const float* Wih1b = (const float*)d_in[13];
  const float* Whh1b = (const float*)d_in[14];
  const float* bih1b = (const float*)d_in[15];
  const float* bhh1b = (const float*)d_in[16];
  const float* fc1W  = (const float*)d_in[17];
  const float* fc1b  = (const float*)d_in[18];
  const float* fc2W  = (const float*)d_in[19];
  const float* fc2b  = (const float*)d_in[20];
  float* out = (float*)d_out;

  size_t y0_bytes = (size_t)BB * TT * 128 * sizeof(YT);
  YT* y0 = (YT*)d_ws;
  float* hT = (float*)((char*)d_ws + ((y0_bytes + 255) & ~(size_t)255));

  dim3 gridL(BB / BT, 2), block(256);
  lstm_l0_kernel<YT><<<gridL, block, 0, stream>>>(
      x, Wih0f, Whh0f, bih0f, bhh0f, Wih0b, Whh0b, bih0b, bhh0b, y0);
  lstm_l1_kernel<YT><<<gridL, block, 0, stream>>>(
      y0, Wih1f, Whh1f, bih1f, bhh1f, Wih1b, Whh1b, bih1b, bhh1b, hT);
  fc_kernel<<<dim3(BB / 4), block, 0, stream>>>(hT, fc1W, fc1b, fc2W, fc2b, out);
}

extern "C" void kernel_launch(void* const* d_in, const int* in_sizes, int n_in,
                              void* d_out, int out_size, void* d_ws, size_t ws_size,
                              hipStream_t stream){
  (void)in_sizes; (void)n_in; (void)out_size;
  size_t need_f32 = (size_t)BB * TT * 128 * sizeof(float) + (size_t)BB * 128 * sizeof(float) + 512;
  if (ws_size >= need_f32){
    run_all<float>(d_in, d_out, d_ws, stream);
  } else {
    run_all<unsigned short>(d_in, d_out, d_ws, stream);
  }
}

// Round 2
// 861.318 us; speedup vs baseline: 7.8120x; 7.8120x over previous
//
#include <hip/hip_runtime.h>
#include <stdint.h>

typedef __attribute__((ext_vector_type(8))) short short8;
typedef __attribute__((ext_vector_type(4))) float f32x4;

#define TT 512
#define BB 1024
#define L0_STR 168   // ushorts per Z row [hhi 64 | hlo 64 | x 32pad]; 336B, 16B-aligned
#define L1_STR 136   // ushorts per Z row [hhi 64 | hlo 64]; 272B, 16B-aligned

__device__ __forceinline__ uint32_t f2bf_u(float f){
  union { float f; uint32_t u; } v; v.f = f;
  return (v.u + 0x7fffu + ((v.u >> 16) & 1u)) >> 16;
}
__device__ __forceinline__ float bf2f(uint32_t w){
  union { uint32_t u; float f; } v; v.u = w << 16; return v.f;
}
__device__ __forceinline__ float fast_rcp(float x){ return __builtin_amdgcn_rcpf(x); }
__device__ __forceinline__ float sigf(float x){ return fast_rcp(1.f + __expf(-x)); }
__device__ __forceinline__ float tanh_f(float x){
  float xx = fminf(fmaxf(x, -10.f), 10.f);
  float e = __expf(2.f * xx);
  return (e - 1.f) * fast_rcp(e + 1.f);
}
// load 8 consecutive fp32, convert to bf16 fragment (A-operand k-chunk)
__device__ __forceinline__ short8 w8f32(const float* p){
  float4 a = *(const float4*)p;
  float4 b = *(const float4*)(p + 4);
  short8 r;
  r[0] = (short)f2bf_u(a.x); r[1] = (short)f2bf_u(a.y);
  r[2] = (short)f2bf_u(a.z); r[3] = (short)f2bf_u(a.w);
  r[4] = (short)f2bf_u(b.x); r[5] = (short)f2bf_u(b.y);
  r[6] = (short)f2bf_u(b.z); r[7] = (short)f2bf_u(b.w);
  return r;
}

// ============ Layer 0: Z = [h_hi(64) | h_lo(64) | x(3 pad 32)], K-tiles: Whh,Whh(lo reuse),X ============
__global__ __launch_bounds__(256, 1) void lstm_l0(
    const float* __restrict__ x,   // [B][3][T]
    const float* __restrict__ Wih_f, const float* __restrict__ Whh_f,
    const float* __restrict__ bih_f, const float* __restrict__ bhh_f,
    const float* __restrict__ Wih_b, const float* __restrict__ Whh_b,
    const float* __restrict__ bih_b, const float* __restrict__ bhh_b,
    unsigned short* __restrict__ y0)  // [B][T][128] bf16
{
  const int tid  = threadIdx.x;
  const int wave = tid >> 6, lane = tid & 63;
  const int quad = lane >> 4, m16 = lane & 15;
  const int dir  = blockIdx.y;
  const int bbase = blockIdx.x * 8;
  const float* Wih = dir ? Wih_b : Wih_f;
  const float* Whh = dir ? Whh_b : Whh_f;
  const float* bih = dir ? bih_b : bih_f;
  const float* bhh = dir ? bhh_b : bhh_f;

  __shared__ __align__(16) unsigned short sZ[2][16][L0_STR];

  // ---- loop-invariant A fragments: lane holds A[m = base + (lane&15)][k = 8*quad + j] ----
  short8 aH[4][2], aX[4];
  f32x4 biasv[4];
  #pragma unroll
  for (int G = 0; G < 4; G++){
    const int row = G * 64 + wave * 16 + m16;
    aH[G][0] = w8f32(Whh + row * 64 + quad * 8);
    aH[G][1] = w8f32(Whh + row * 64 + 32 + quad * 8);
    #pragma unroll
    for (int j = 0; j < 8; j++){
      float w = (quad == 0 && j < 3) ? Wih[row * 3 + j] : 0.f;
      aX[G][j] = (short)f2bf_u(w);
    }
    const int rb = G * 64 + wave * 16 + quad * 4;   // C-layout row base
    biasv[G][0] = bih[rb + 0] + bhh[rb + 0];
    biasv[G][1] = bih[rb + 1] + bhh[rb + 1];
    biasv[G][2] = bih[rb + 2] + bhh[rb + 2];
    biasv[G][3] = bih[rb + 3] + bhh[rb + 3];
  }

  // zero both Z buffers (h0 = 0, x pads = 0, dup rows = 0)
  for (int idx = tid; idx < 2 * 16 * L0_STR; idx += 256)
    ((unsigned short*)sZ)[idx] = 0;
  __syncthreads();

  // seed x(t0) into buffer 0; prefetch x(t1)
  const int xn = tid / 3, xd = tid % 3;
  const bool isx = (tid < 24);
  float xv = 0.f;
  if (isx){
    const int t0 = dir ? (TT - 1) : 0;
    sZ[0][xn][128 + xd] = (unsigned short)f2bf_u(x[(size_t)(bbase + xn) * 1536 + xd * 512 + t0]);
    const int t1 = dir ? (TT - 2) : 1;
    xv = x[(size_t)(bbase + xn) * 1536 + xd * 512 + t1];
  }
  __syncthreads();

  float c[4] = {0.f, 0.f, 0.f, 0.f};
  const int u0 = wave * 16 + quad * 4;

  for (int s = 0; s < TT; s++){
    const int p = s & 1, p1 = p ^ 1;
    const int t = dir ? (TT - 1 - s) : s;

    // B fragments: lane holds Z[k = 8*quad + j][n = lane&15]
    short8 bh0 = *(const short8*)&sZ[p][m16][      quad * 8];
    short8 bh1 = *(const short8*)&sZ[p][m16][ 32 + quad * 8];
    short8 bl0 = *(const short8*)&sZ[p][m16][ 64 + quad * 8];
    short8 bl1 = *(const short8*)&sZ[p][m16][ 96 + quad * 8];
    short8 bx  = *(const short8*)&sZ[p][m16][128 + quad * 8];

    f32x4 acc[4];
    #pragma unroll
    for (int G = 0; G < 4; G++){
      acc[G] = biasv[G];
      acc[G] = __builtin_amdgcn_mfma_f32_16x16x32_bf16(aH[G][0], bh0, acc[G], 0, 0, 0);
      acc[G] = __builtin_amdgcn_mfma_f32_16x16x32_bf16(aH[G][1], bh1, acc[G], 0, 0, 0);
      acc[G] = __builtin_amdgcn_mfma_f32_16x16x32_bf16(aH[G][0], bl0, acc[G], 0, 0, 0);
      acc[G] = __builtin_amdgcn_mfma_f32_16x16x32_bf16(aH[G][1], bl1, acc[G], 0, 0, 0);
      acc[G] = __builtin_amdgcn_mfma_f32_16x16x32_bf16(aX[G],    bx,  acc[G], 0, 0, 0);
    }

    // gate nonlinearity + state update (lane owns units u0..u0+3, batch col m16)
    float hval[4];
    #pragma unroll
    for (int r = 0; r < 4; r++){
      float ip = sigf(acc[0][r]);
      float fp = sigf(acc[1][r]);
      float gp = tanh_f(acc[2][r]);
      float op = sigf(acc[3][r]);
      c[r] = fmaf(fp, c[r], ip * gp);
      hval[r] = op * tanh_f(c[r]);
    }
    uint32_t h0 = f2bf_u(hval[0]), h1 = f2bf_u(hval[1]),
             h2 = f2bf_u(hval[2]), h3 = f2bf_u(hval[3]);
    uint32_t l0b = f2bf_u(hval[0] - bf2f(h0)), l1b = f2bf_u(hval[1] - bf2f(h1)),
             l2b = f2bf_u(hval[2] - bf2f(h2)), l3b = f2bf_u(hval[3] - bf2f(h3));

    *(uint2*)&sZ[p1][m16][u0]      = make_uint2(h0  | (h1 << 16), h2  | (h3 << 16));
    *(uint2*)&sZ[p1][m16][64 + u0] = make_uint2(l0b | (l1b << 16), l2b | (l3b << 16));
    if (isx){
      sZ[p1][xn][128 + xd] = (unsigned short)f2bf_u(xv);
      if (s + 2 < TT){
        const int t2 = dir ? (TT - 3 - s) : (s + 2);
        xv = x[(size_t)(bbase + xn) * 1536 + xd * 512 + t2];
      }
    }
    if (m16 < 8){
      *(uint2*)(y0 + ((size_t)(bbase + m16) * TT + t) * 128 + dir * 64 + u0) =
          make_uint2(h0 | (h1 << 16), h2 | (h3 << 16));
    }
    __syncthreads();
  }
}

// ============ Layer 1: Z = [y0(128 from global) | h_hi(64) | h_lo(64)] ============
__global__ __launch_bounds__(256, 1) void lstm_l1(
    const unsigned short* __restrict__ y0,  // [B][T][128] bf16
    const float* __restrict__ Wih_f, const float* __restrict__ Whh_f,
    const float* __restrict__ bih_f, const float* __restrict__ bhh_f,
    const float* __restrict__ Wih_b, const float* __restrict__ Whh_b,
    const float* __restrict__ bih_b, const float* __restrict__ bhh_b,
    float* __restrict__ hT)                 // [B][128] fp32
{
  const int tid  = threadIdx.x;
  const int wave = tid >> 6, lane = tid & 63;
  const int quad = lane >> 4, m16 = lane & 15;
  const int dir  = blockIdx.y;
  const int bbase = blockIdx.x * 8;
  const float* Wih = dir ? Wih_b : Wih_f;
  const float* Whh = dir ? Whh_b : Whh_f;
  const float* bih = dir ? bih_b : bih_f;
  const float* bhh = dir ? bhh_b : bhh_f;

  __shared__ __align__(16) unsigned short sZ[2][16][L1_STR];

  short8 aY[4][4], aH[4][2];
  f32x4 biasv[4];
  #pragma unroll
  for (int G = 0; G < 4; G++){
    const int row = G * 64 + wave * 16 + m16;
    #pragma unroll
    for (int kt = 0; kt < 4; kt++)
      aY[G][kt] = w8f32(Wih + row * 128 + kt * 32 + quad * 8);
    aH[G][0] = w8f32(Whh + row * 64 + quad * 8);
    aH[G][1] = w8f32(Whh + row * 64 + 32 + quad * 8);
    const int rb = G * 64 + wave * 16 + quad * 4;
    biasv[G][0] = bih[rb + 0] + bhh[rb + 0];
    biasv[G][1] = bih[rb + 1] + bhh[rb + 1];
    biasv[G][2] = bih[rb + 2] + bhh[rb + 2];
    biasv[G][3] = bih[rb + 3] + bhh[rb + 3];
  }

  for (int idx = tid; idx < 2 * 16 * L1_STR; idx += 256)
    ((unsigned short*)sZ)[idx] = 0;
  __syncthreads();

  // y0 B-fragments straight from global (16B/lane, k-contiguous); duplicate batches for n>=8
  const size_t brow = (size_t)(bbase + (m16 & 7)) * TT;
  short8 by[4], byn[4];
  {
    const int t0 = dir ? (TT - 1) : 0;
    const unsigned short* yb = y0 + (brow + t0) * 128;
    #pragma unroll
    for (int kt = 0; kt < 4; kt++) by[kt] = *(const short8*)(yb + kt * 32 + quad * 8);
  }

  float c[4] = {0.f, 0.f, 0.f, 0.f};
  const int u0 = wave * 16 + quad * 4;

  for (int s = 0; s < TT; s++){
    const int p = s & 1, p1 = p ^ 1;

    // prefetch next step's y0 fragments (overlaps MFMA + nonlin)
    {
      const int sn = (s + 1 < TT) ? (s + 1) : s;
      const int tn = dir ? (TT - 1 - sn) : sn;
      const unsigned short* yb = y0 + (brow + tn) * 128;
      #pragma unroll
      for (int kt = 0; kt < 4; kt++) byn[kt] = *(const short8*)(yb + kt * 32 + quad * 8);
    }

    short8 bh0 = *(const short8*)&sZ[p][m16][     quad * 8];
    short8 bh1 = *(const short8*)&sZ[p][m16][32 + quad * 8];
    short8 bl0 = *(const short8*)&sZ[p][m16][64 + quad * 8];
    short8 bl1 = *(const short8*)&sZ[p][m16][96 + quad * 8];

    f32x4 acc[4];
    #pragma unroll
    for (int G = 0; G < 4; G++){
      acc[G] = biasv[G];
      acc[G] = __builtin_amdgcn_mfma_f32_16x16x32_bf16(aY[G][0], by[0], acc[G], 0, 0, 0);
      acc[G] = __builtin_amdgcn_mfma_f32_16x16x32_bf16(aY[G][1], by[1], acc[G], 0, 0, 0);
      acc[G] = __builtin_amdgcn_mfma_f32_16x16x32_bf16(aY[G][2], by[2], acc[G], 0, 0, 0);
      acc[G] = __builtin_amdgcn_mfma_f32_16x16x32_bf16(aY[G][3], by[3], acc[G], 0, 0, 0);
      acc[G] = __builtin_amdgcn_mfma_f32_16x16x32_bf16(aH[G][0], bh0,  acc[G], 0, 0, 0);
      acc[G] = __builtin_amdgcn_mfma_f32_16x16x32_bf16(aH[G][1], bh1,  acc[G], 0, 0, 0);
      acc[G] = __builtin_amdgcn_mfma_f32_16x16x32_bf16(aH[G][0], bl0,  acc[G], 0, 0, 0);
      acc[G] = __builtin_amdgcn_mfma_f32_16x16x32_bf16(aH[G][1], bl1,  acc[G], 0, 0, 0);
    }

    float hval[4];
    #pragma unroll
    for (int r = 0; r < 4; r++){
      float ip = sigf(acc[0][r]);
      float fp = sigf(acc[1][r]);
      float gp = tanh_f(acc[2][r]);
      float op = sigf(acc[3][r]);
      c[r] = fmaf(fp, c[r], ip * gp);
      hval[r] = op * tanh_f(c[r]);
    }
    uint32_t h0 = f2bf_u(hval[0]), h1 = f2bf_u(hval[1]),
             h2 = f2bf_u(hval[2]), h3 = f2bf_u(hval[3]);
    uint32_t l0b = f2bf_u(hval[0] - bf2f(h0)), l1b = f2bf_u(hval[1] - bf2f(h1)),
             l2b = f2bf_u(hval[2] - bf2f(h2)), l3b = f2bf_u(hval[3] - bf2f(h3));

    *(uint2*)&sZ[p1][m16][u0]      = make_uint2(h0  | (h1 << 16), h2  | (h3 << 16));
    *(uint2*)&sZ[p1][m16][64 + u0] = make_uint2(l0b | (l1b << 16), l2b | (l3b << 16));

    if (s == TT - 1 && m16 < 8){
      float4 hv; hv.x = hval[0]; hv.y = hval[1]; hv.z = hval[2]; hv.w = hval[3];
      *(float4*)(hT + (size_t)(bbase + m16) * 128 + dir * 64 + u0) = hv;
    }
    __syncthreads();
    #pragma unroll
    for (int kt = 0; kt < 4; kt++) by[kt] = byn[kt];
  }
}

// ============ FC head ============
__global__ __launch_bounds__(256, 1) void fc_kernel(
    const float* __restrict__ hT,
    const float* __restrict__ w1, const float* __restrict__ b1,
    const float* __restrict__ w2, const float* __restrict__ b2,
    float* __restrict__ out)
{
  __shared__ float sh[4][64];
  const int wave = threadIdx.x >> 6, lane = threadIdx.x & 63;
  const int b = blockIdx.x * 4 + wave;
  float acc = b1[lane];
  const float* hrow = hT + (size_t)b * 128;
  #pragma unroll
  for (int k = 0; k < 128; k += 4){
    float4 h4 = *(const float4*)(hrow + k);
    float4 w4 = *(const float4*)(w1 + lane * 128 + k);
    acc = fmaf(w4.x, h4.x, acc);
    acc = fmaf(w4.y, h4.y, acc);
    acc = fmaf(w4.z, h4.z, acc);
    acc = fmaf(w4.w, h4.w, acc);
  }
  sh[wave][lane] = fmaxf(acc, 0.f);
  __syncthreads();
  if (lane < 2){
    float a = b2[lane];
    #pragma unroll
    for (int k = 0; k < 64; k++) a = fmaf(w2[lane * 64 + k], sh[wave][k], a);
    out[(size_t)b * 2 + lane] = a;
  }
}

extern "C" void kernel_launch(void* const* d_in, const int* in_sizes, int n_in,
                              void* d_out, int out_size, void* d_ws, size_t ws_size,
                              hipStream_t stream){
  (void)in_sizes; (void)n_in; (void)out_size; (void)ws_size;
  const float* x     = (const float*)d_in[0];
  const float* Wih0f = (const float*)d_in[1];
  const float* Whh0f = (const float*)d_in[2];
  const float* bih0f = (const float*)d_in[3];
  const float* bhh0f = (const float*)d_in[4];
  const float* Wih0b = (const float*)d_in[5];
  const float* Whh0b = (const float*)d_in[6];
  const float* bih0b = (const float*)d_in[7];
  const float* bhh0b = (const float*)d_in[8];
  const float* Wih1f = (const float*)d_in[9];
  const float* Whh1f = (const float*)d_in[10];
  const float* bih1f = (const float*)d_in[11];
  const float* bhh1f = (const float*)d_in[12];
  const float* Wih1b = (const float*)d_in[13];
  const float* Whh1b = (const float*)d_in[14];
  const float* bih1b = (const float*)d_in[15];
  const float* bhh1b = (const float*)d_in[16];
  const float* fc1W  = (const float*)d_in[17];
  const float* fc1b  = (const float*)d_in[18];
  const float* fc2W  = (const float*)d_in[19];
  const float* fc2b  = (const float*)d_in[20];
  float* out = (float*)d_out;

  unsigned short* y0 = (unsigned short*)d_ws;                  // 134,217,728 B
  float* hT = (float*)((char*)d_ws + (size_t)BB * TT * 128 * 2);

  dim3 grid(BB / 8, 2), block(256);
  lstm_l0<<<grid, block, 0, stream>>>(x, Wih0f, Whh0f, bih0f, bhh0f,
                                      Wih0b, Whh0b, bih0b, bhh0b, y0);
  lstm_l1<<<grid, block, 0, stream>>>(y0, Wih1f, Whh1f, bih1f, bhh1f,
                                      Wih1b, Whh1b, bih1b, bhh1b, hT);
  fc_kernel<<<dim3(BB / 4), block, 0, stream>>>(hT, fc1W, fc1b, fc2W, fc2b, out);
}